// Round 1
// baseline (187.522 us; speedup 1.0000x reference)
//
#include <hip/hip_runtime.h>

#define BB 4
#define SS 2048
#define EE 1024

typedef _Float16 f16;
typedef _Float16 f16x8 __attribute__((ext_vector_type(8)));
typedef _Float16 f16x4 __attribute__((ext_vector_type(4)));
typedef float f32x4 __attribute__((ext_vector_type(4)));

typedef const __attribute__((address_space(1))) void* gas_ptr;
typedef __attribute__((address_space(3))) void* las_ptr;

__device__ __forceinline__ void gl_lds16(const void* g, void* l) {
  __builtin_amdgcn_global_load_lds((gas_ptr)g, (las_ptr)l, 16, 0, 0);
}

// ---------------- fp32 -> fp16 convert ----------------
__global__ __launch_bounds__(256) void cvt_f32_f16(const float* __restrict__ in,
                                                   f16* __restrict__ out, int n4) {
  int idx = blockIdx.x * blockDim.x + threadIdx.x;
  int stride = gridDim.x * blockDim.x;
  for (int i = idx; i < n4; i += stride) {
    float4 v = ((const float4*)in)[i];
    f16x4 o;
    o[0] = (f16)v.x; o[1] = (f16)v.y; o[2] = (f16)v.z; o[3] = (f16)v.w;
    ((f16x4*)out)[i] = o;
  }
}

// ---------------- GEMM, B^T layout: C[M,N] = A[M,K] * Bm[N,K]^T ----------------
// EPI 0: f16 store of acc*scale.  EPI 1: f32 store of acc*scale + bias[col].
template <int EPI>
__global__ __launch_bounds__(256) void gemm_bt(
    const f16* __restrict__ A, const f16* __restrict__ Bm, void* __restrict__ C,
    const float* __restrict__ bias, int K, int N, float scale,
    long sAb, long sBb, long sCb) {
  __shared__ f16 As[128 * 64];
  __shared__ f16 Bs[128 * 64];
  const int tid = threadIdx.x;
  const int lane = tid & 63;
  const int wave = tid >> 6;
  const int wm = wave >> 1, wn = wave & 1;
  const long m0 = (long)blockIdx.y * 128;
  const long n0 = (long)blockIdx.x * 128;
  A += sAb * blockIdx.z;
  Bm += sBb * blockIdx.z;

  f32x4 acc[4][4] = {};

  const int nkt = K >> 6;  // BK = 64
  for (int kt = 0; kt < nkt; ++kt) {
#pragma unroll
    for (int r = 0; r < 4; ++r) {
      int idx = tid + r * 256;      // [0, 1024)
      int row = idx >> 3;           // 128 tile rows
      int c = idx & 7;              // 8 x 16B chunks per 64-elem row
      gl_lds16(A + (m0 + row) * K + kt * 64 + c * 8, (char*)As + idx * 16);
      gl_lds16(Bm + (n0 + row) * K + kt * 64 + c * 8, (char*)Bs + idx * 16);
    }
    __syncthreads();  // drains vmcnt -> staged tiles visible
#pragma unroll
    for (int kk = 0; kk < 2; ++kk) {
      const int koff = kk * 32 + (lane >> 4) * 8;  // element offset in row
      f16x8 af[4], bf[4];
#pragma unroll
      for (int m = 0; m < 4; ++m) {
        int row = wm * 64 + m * 16 + (lane & 15);
        af[m] = *(const f16x8*)(As + row * 64 + koff);
      }
#pragma unroll
      for (int n = 0; n < 4; ++n) {
        int row = wn * 64 + n * 16 + (lane & 15);
        bf[n] = *(const f16x8*)(Bs + row * 64 + koff);
      }
#pragma unroll
      for (int m = 0; m < 4; ++m)
#pragma unroll
        for (int n = 0; n < 4; ++n)
          acc[m][n] = __builtin_amdgcn_mfma_f32_16x16x32_f16(af[m], bf[n], acc[m][n], 0, 0, 0);
    }
    __syncthreads();  // all waves done reading before next stage overwrites
  }

  // C/D layout: col = lane&15, row = (lane>>4)*4 + reg (m89-verified, dtype-indep)
  const int crow = wm * 64 + (lane >> 4) * 4;
  const int ccol = wn * 64 + (lane & 15);
  if (EPI == 0) {
    f16* Co = (f16*)C + sCb * blockIdx.z;
#pragma unroll
    for (int m = 0; m < 4; ++m)
#pragma unroll
      for (int n = 0; n < 4; ++n)
#pragma unroll
        for (int j = 0; j < 4; ++j)
          Co[(m0 + crow + m * 16 + j) * N + (n0 + ccol + n * 16)] =
              (f16)(acc[m][n][j] * scale);
  } else {
    float* Co = (float*)C + sCb * blockIdx.z;
#pragma unroll
    for (int m = 0; m < 4; ++m)
#pragma unroll
      for (int n = 0; n < 4; ++n) {
        float bv = bias[n0 + ccol + n * 16];
#pragma unroll
        for (int j = 0; j < 4; ++j)
          Co[(m0 + crow + m * 16 + j) * N + (n0 + ccol + n * 16)] =
              acc[m][n][j] * scale + bv;
      }
  }
}

// ---------------- masked row softmax, in place on f16 scores ----------------
__global__ __launch_bounds__(256) void softmax_mask(f16* __restrict__ sc,
                                                    const int* __restrict__ mask) {
  const int row = blockIdx.x;  // b*SS + q
  const int b = row >> 11;     // SS = 2048
  f16* p = sc + (long)row * SS;
  const int* mk = mask + (b << 11);
  const int tid = threadIdx.x;
  const int lane = tid & 63, wave = tid >> 6;

  f16x8 v = ((const f16x8*)p)[tid];
  int4 mv0 = ((const int4*)mk)[tid * 2];
  int4 mv1 = ((const int4*)mk)[tid * 2 + 1];
  int mi[8] = {mv0.x, mv0.y, mv0.z, mv0.w, mv1.x, mv1.y, mv1.z, mv1.w};

  float x[8];
  float mx = -3.0e38f;
#pragma unroll
  for (int j = 0; j < 8; ++j) {
    x[j] = mi[j] ? (float)v[j] : -3.0e38f;
    mx = fmaxf(mx, x[j]);
  }
#pragma unroll
  for (int o = 32; o >= 1; o >>= 1) mx = fmaxf(mx, __shfl_xor(mx, o));
  __shared__ float redm[4], reds[4];
  if (lane == 0) redm[wave] = mx;
  __syncthreads();
  mx = fmaxf(fmaxf(redm[0], redm[1]), fmaxf(redm[2], redm[3]));

  float e[8];
  float s = 0.f;
#pragma unroll
  for (int j = 0; j < 8; ++j) {
    e[j] = mi[j] ? __expf(x[j] - mx) : 0.f;
    s += e[j];
  }
#pragma unroll
  for (int o = 32; o >= 1; o >>= 1) s += __shfl_xor(s, o);
  if (lane == 0) reds[wave] = s;
  __syncthreads();
  s = reds[0] + reds[1] + reds[2] + reds[3];
  const float inv = 1.f / s;
  f16x8 o8;
#pragma unroll
  for (int j = 0; j < 8; ++j) o8[j] = (f16)(e[j] * inv);
  ((f16x8*)p)[tid] = o8;
}

// ---------------- [B][S][E] -> [B][E][S] transpose (f16) ----------------
__global__ void transpose_bse(const f16* __restrict__ in, f16* __restrict__ out) {
  __shared__ f16 t[32][33];
  const long b = blockIdx.z;
  const f16* ip = in + b * (long)SS * EE;
  f16* op = out + b * (long)EE * SS;
  const int e0 = blockIdx.x * 32, s0 = blockIdx.y * 32;
  for (int i = threadIdx.y; i < 32; i += 8)
    t[i][threadIdx.x] = ip[(long)(s0 + i) * EE + e0 + threadIdx.x];
  __syncthreads();
  for (int i = threadIdx.y; i < 32; i += 8)
    op[(long)(e0 + i) * SS + s0 + threadIdx.x] = t[threadIdx.x][i];
}

extern "C" void kernel_launch(void* const* d_in, const int* in_sizes, int n_in,
                              void* d_out, int out_size, void* d_ws, size_t ws_size,
                              hipStream_t stream) {
  const float* V = (const float*)d_in[0];    // values
  const float* Kin = (const float*)d_in[1];  // keys
  const float* Q = (const float*)d_in[2];    // query
  const int* mask = (const int*)d_in[3];     // [B,1,S] int32
  const float* W = (const float*)d_in[4];    // [E,E]
  const float* bias = (const float*)d_in[5]; // [E]
  float* out = (float*)d_out;

  const long NE = (long)BB * SS * EE;  // 8388608
  f16* Qh = (f16*)d_ws;                // NE
  f16* Kh = Qh + NE;                   // NE
  f16* Vh = Kh + NE;                   // NE (reused as VWt after GEMM1)
  f16* Wh = Vh + NE;                   // EE*EE
  f16* VW = Wh + (long)EE * EE;        // NE
  f16* P = VW + NE;                    // 2*NE (B*S*S)
  f16* VWt = Vh;

  cvt_f32_f16<<<1024, 256, 0, stream>>>(Q, Qh, (int)(NE / 4));
  cvt_f32_f16<<<1024, 256, 0, stream>>>(Kin, Kh, (int)(NE / 4));
  cvt_f32_f16<<<1024, 256, 0, stream>>>(V, Vh, (int)(NE / 4));
  cvt_f32_f16<<<256, 256, 0, stream>>>(W, Wh, (EE * EE) / 4);

  // VW = V @ W^T : [B*S, E], K = E
  gemm_bt<0><<<dim3(EE / 128, (BB * SS) / 128, 1), 256, 0, stream>>>(
      Vh, Wh, VW, nullptr, EE, EE, 1.0f, 0, 0, 0);

  // VWt[b][e][s] = VW[b][s][e]
  transpose_bse<<<dim3(EE / 32, SS / 32, BB), dim3(32, 8), 0, stream>>>(VW, VWt);

  // scores = Q K^T / sqrt(E) : per-batch [S, S], K = E
  gemm_bt<0><<<dim3(SS / 128, SS / 128, BB), 256, 0, stream>>>(
      Qh, Kh, P, nullptr, EE, SS, 1.0f / 32.0f,
      (long)SS * EE, (long)SS * EE, (long)SS * SS);

  // P = softmax(mask(scores)) in place
  softmax_mask<<<BB * SS, 256, 0, stream>>>(P, mask);

  // out = P @ VW + b : per-batch [S, E], K = S
  gemm_bt<1><<<dim3(EE / 128, SS / 128, BB), 256, 0, stream>>>(
      P, VWt, out, bias, SS, EE, 1.0f,
      (long)SS * SS, (long)EE * SS, (long)SS * EE);
}

// Round 3
// 174.049 us; speedup vs baseline: 1.0774x; 1.0774x over previous
//
#include <hip/hip_runtime.h>

#define BB 4
#define SS 2048
#define EE 1024

typedef _Float16 f16;
typedef _Float16 f16x8 __attribute__((ext_vector_type(8)));
typedef float f32x4 __attribute__((ext_vector_type(4)));

typedef const __attribute__((address_space(1))) void* gas_ptr;
typedef __attribute__((address_space(3))) void* las_ptr;

__device__ __forceinline__ void gl_lds16(const void* g, void* l) {
  __builtin_amdgcn_global_load_lds((gas_ptr)g, (las_ptr)l, 16, 0, 0);
}

#define BAR() __builtin_amdgcn_s_barrier()
#define PRIO1() __builtin_amdgcn_s_setprio(1)
#define PRIO0() __builtin_amdgcn_s_setprio(0)
#define WAITV8() asm volatile("s_waitcnt vmcnt(8)" ::: "memory")
#define WAITV4() asm volatile("s_waitcnt vmcnt(4)" ::: "memory")
#define WAITV0() asm volatile("s_waitcnt vmcnt(0)" ::: "memory")

// ---------------- fp32 -> fp16 converts ----------------
__global__ __launch_bounds__(256) void cvt_f32_f16(const float* __restrict__ in,
                                                   f16* __restrict__ out, int n8) {
  int idx = blockIdx.x * blockDim.x + threadIdx.x;
  int stride = gridDim.x * blockDim.x;
  for (long i = idx; i < n8; i += stride) {
    float4 v0 = ((const float4*)in)[i * 2];
    float4 v1 = ((const float4*)in)[i * 2 + 1];
    f16x8 o;
    o[0] = (f16)v0.x; o[1] = (f16)v0.y; o[2] = (f16)v0.z; o[3] = (f16)v0.w;
    o[4] = (f16)v1.x; o[5] = (f16)v1.y; o[6] = (f16)v1.z; o[7] = (f16)v1.w;
    ((f16x8*)out)[i] = o;
  }
}

__global__ __launch_bounds__(256) void cvt3(const float* __restrict__ x0,
                                            const float* __restrict__ x1,
                                            const float* __restrict__ x2,
                                            f16* __restrict__ o0, f16* __restrict__ o1,
                                            f16* __restrict__ o2) {
  const float* in = (blockIdx.y == 0) ? x0 : (blockIdx.y == 1) ? x1 : x2;
  f16* out = (blockIdx.y == 0) ? o0 : (blockIdx.y == 1) ? o1 : o2;
  long i = (long)blockIdx.x * 256 + threadIdx.x;  // 8 f32 per thread
  float4 v0 = ((const float4*)in)[i * 2];
  float4 v1 = ((const float4*)in)[i * 2 + 1];
  f16x8 o;
  o[0] = (f16)v0.x; o[1] = (f16)v0.y; o[2] = (f16)v0.z; o[3] = (f16)v0.w;
  o[4] = (f16)v1.x; o[5] = (f16)v1.y; o[6] = (f16)v1.z; o[7] = (f16)v1.w;
  ((f16x8*)out)[i] = o;
}

// ---------------- 256x256 8-phase GEMM, B^T layout ----------------
// C[M,N] = A[M,K] * Bm[N,K]^T.  EPI 0: f16 store acc*scale. EPI 1: f32 +bias.
// 8 waves (2M x 4N), BK=64, 2 K-tiles/iter, 8 phases/iter, 128 KiB LDS dbuf.
// Swizzle: 16B-slot ^= (row&7) on global SOURCE (gload_lds dest linear) and
// on ds_read address (both-sides involution).
// Gate discipline (R3 fix): first ds_read of a tile only after
// {own vmcnt wait covering that tile's 8 loads -> s_barrier}.

__device__ __forceinline__ void stage64(const f16* g, long K, f16* l, int h, int t) {
  int rr = t >> 3, sp = t & 7;
  int row = h * 64 + rr;
  int sl = sp ^ (rr & 7);
  gl_lds16(g + (long)row * K + (sl << 3), (char*)l + ((row << 6) + (sp << 3)) * 2);
}

__device__ __forceinline__ void read_a(f16x8 (&d)[4][2], const f16* base, int q,
                                       int wm, int l15, int l4) {
#pragma unroll
  for (int mf = 0; mf < 4; ++mf)
#pragma unroll
    for (int kk = 0; kk < 2; ++kk) {
      int row = wm * 128 + (q * 4 + mf) * 16 + l15;
      int sl = kk * 4 + l4;
      d[mf][kk] = *(const f16x8*)(base + row * 64 + ((sl ^ (row & 7)) << 3));
    }
}

__device__ __forceinline__ void read_b(f16x8 (&d)[2][2], const f16* base, int nh,
                                       int wn, int l15, int l4) {
#pragma unroll
  for (int nf = 0; nf < 2; ++nf)
#pragma unroll
    for (int kk = 0; kk < 2; ++kk) {
      int row = wn * 64 + (nh * 2 + nf) * 16 + l15;
      int sl = kk * 4 + l4;
      d[nf][kk] = *(const f16x8*)(base + row * 64 + ((sl ^ (row & 7)) << 3));
    }
}

__device__ __forceinline__ void mfma_q(f32x4 (&acc)[8][4], const f16x8 (&Af)[4][2],
                                       const f16x8 (&Bf)[2][2], int q, int nh) {
#pragma unroll
  for (int mf = 0; mf < 4; ++mf)
#pragma unroll
    for (int nf = 0; nf < 2; ++nf)
#pragma unroll
      for (int kk = 0; kk < 2; ++kk)
        acc[q * 4 + mf][nh * 2 + nf] = __builtin_amdgcn_mfma_f32_16x16x32_f16(
            Af[mf][kk], Bf[nf][kk], acc[q * 4 + mf][nh * 2 + nf], 0, 0, 0);
}

template <int EPI>
__global__ __launch_bounds__(512, 1) void gemm256(
    const f16* __restrict__ A, const f16* __restrict__ Bm, void* __restrict__ C,
    const float* __restrict__ bias, int K, int N, float scale,
    long sAb, long sBb, long sCb) {
  extern __shared__ f16 lds[];
  f16* As0 = lds;
  f16* As1 = lds + 16384;
  f16* Bs0 = lds + 32768;
  f16* Bs1 = lds + 49152;
  const int tid = threadIdx.x;
  const int lane = tid & 63, wv = tid >> 6;
  const int wm = wv >> 2, wn = wv & 3;
  const int l15 = lane & 15, l4 = lane >> 4;
  const long m0 = (long)blockIdx.y * 256;
  const long n0 = (long)blockIdx.x * 256;
  const f16* Ag = A + sAb * blockIdx.z + m0 * K;
  const f16* Bg = Bm + sBb * blockIdx.z + n0 * K;

  const long crow = m0 + wm * 128 + l4 * 4;
  const long ccol = n0 + wn * 64 + l15;

  // EPI=1: preload bias BEFORE the prologue so mid-loop vmcnt counting stays
  // exact (+4 oldest loads, absorbed by the first drain-to-8).
  float bv[4];
  if (EPI == 1) {
#pragma unroll
    for (int nf = 0; nf < 4; ++nf) bv[nf] = bias[ccol + nf * 16];
    asm volatile("" ::: "memory");
  }

  f32x4 acc[8][4] = {};
  f16x8 a[4][2], b[2][2], b2[2][2];

  const int NT = K >> 6;
  const int NIT = NT >> 1;

  // prologue: tile0 -> buf0 (8 loads), tile1 -> buf1 (8 loads)
#pragma unroll
  for (int h = 0; h < 4; ++h) stage64(Bg, K, Bs0, h, tid);
#pragma unroll
  for (int h = 0; h < 4; ++h) stage64(Ag, K, As0, h, tid);
#pragma unroll
  for (int h = 0; h < 4; ++h) stage64(Bg + 64, K, Bs1, h, tid);
#pragma unroll
  for (int h = 0; h < 4; ++h) stage64(Ag + 64, K, As1, h, tid);
  WAITV8();  // own tile-0 loads landed...
  BAR();     // ...and everyone else's too -> tile 0 readable

  for (int i = 0; i < NIT; ++i) {
    int t2 = 2 * i + 2, t3 = 2 * i + 3;
    long k2 = (long)((t2 < NT) ? t2 : NT - 1) << 6;
    long k3 = (long)((t3 < NT) ? t3 : NT - 1) << 6;
    // ---- K-tile a = 2i (buf0, gated): phases P0..P3 ----
    read_a(a, As0, 0, wm, l15, l4);
    read_b(b, Bs0, 0, wn, l15, l4);
    BAR(); PRIO1(); mfma_q(acc, a, b, 0, 0); PRIO0(); BAR();
    read_b(b2, Bs0, 1, wn, l15, l4);
    BAR(); PRIO1(); mfma_q(acc, a, b2, 0, 1); PRIO0(); BAR();
    read_a(a, As0, 1, wm, l15, l4);
    stage64(Bg + k2, K, Bs0, 0, tid); stage64(Bg + k2, K, Bs0, 1, tid);  // B free after P1
    BAR(); PRIO1(); mfma_q(acc, a, b2, 1, 1); PRIO0(); BAR();
    stage64(Bg + k2, K, Bs0, 2, tid); stage64(Bg + k2, K, Bs0, 3, tid);
    BAR(); PRIO1(); mfma_q(acc, a, b, 1, 0); PRIO0();
    WAITV4();  // drain tile-b's 8 (oldest); 4 new Bs0 stages stay in flight
    BAR();     // tile b readable by all waves
    // ---- K-tile b = 2i+1 (buf1, gated): phases P4..P7 ----
    read_a(a, As1, 0, wm, l15, l4);
    read_b(b, Bs1, 0, wn, l15, l4);
    stage64(Ag + k2, K, As0, 0, tid); stage64(Ag + k2, K, As0, 1, tid);  // A free after P2
    BAR(); PRIO1(); mfma_q(acc, a, b, 0, 0); PRIO0(); BAR();
    read_b(b2, Bs1, 1, wn, l15, l4);
    stage64(Ag + k2, K, As0, 2, tid); stage64(Ag + k2, K, As0, 3, tid);
    BAR(); PRIO1(); mfma_q(acc, a, b2, 0, 1); PRIO0(); BAR();
    read_a(a, As1, 1, wm, l15, l4);
    stage64(Bg + k3, K, Bs1, 0, tid); stage64(Bg + k3, K, Bs1, 1, tid);
    BAR(); PRIO1(); mfma_q(acc, a, b2, 1, 1); PRIO0(); BAR();
    stage64(Bg + k3, K, Bs1, 2, tid); stage64(Bg + k3, K, Bs1, 3, tid);
    stage64(Ag + k3, K, As1, 0, tid); stage64(Ag + k3, K, As1, 1, tid);
    stage64(Ag + k3, K, As1, 2, tid); stage64(Ag + k3, K, As1, 3, tid);
    BAR(); PRIO1(); mfma_q(acc, a, b, 1, 0); PRIO0();
    WAITV8();  // drain next tile-a's 8 (oldest of the 16 in flight)
    BAR();     // next tile-a readable
  }
  WAITV0();  // drain clamped tail stages before WG exit / epilogue

  // epilogue: C/D layout col=lane&15, row=(lane>>4)*4+j
  if (EPI == 0) {
    f16* Co = (f16*)C + sCb * blockIdx.z;
#pragma unroll
    for (int mf = 0; mf < 8; ++mf)
#pragma unroll
      for (int nf = 0; nf < 4; ++nf)
#pragma unroll
        for (int j = 0; j < 4; ++j)
          Co[(crow + mf * 16 + j) * N + ccol + nf * 16] = (f16)(acc[mf][nf][j] * scale);
  } else {
    float* Co = (float*)C + sCb * blockIdx.z;
#pragma unroll
    for (int mf = 0; mf < 8; ++mf)
#pragma unroll
      for (int nf = 0; nf < 4; ++nf)
#pragma unroll
        for (int j = 0; j < 4; ++j)
          Co[(crow + mf * 16 + j) * N + ccol + nf * 16] = acc[mf][nf][j] * scale + bv[nf];
  }
}

// ---------------- masked row softmax, in place on f16 scores ----------------
__global__ __launch_bounds__(256) void softmax_mask(f16* __restrict__ sc,
                                                    const int* __restrict__ mask) {
  const int row = blockIdx.x;  // b*SS + q
  const int b = row >> 11;     // SS = 2048
  f16* p = sc + (long)row * SS;
  const int* mk = mask + (b << 11);
  const int tid = threadIdx.x;
  const int lane = tid & 63, wave = tid >> 6;

  f16x8 v = ((const f16x8*)p)[tid];
  int4 mv0 = ((const int4*)mk)[tid * 2];
  int4 mv1 = ((const int4*)mk)[tid * 2 + 1];
  int mi[8] = {mv0.x, mv0.y, mv0.z, mv0.w, mv1.x, mv1.y, mv1.z, mv1.w};

  float x[8];
  float mx = -3.0e38f;
#pragma unroll
  for (int j = 0; j < 8; ++j) {
    x[j] = mi[j] ? (float)v[j] : -3.0e38f;
    mx = fmaxf(mx, x[j]);
  }
#pragma unroll
  for (int o = 32; o >= 1; o >>= 1) mx = fmaxf(mx, __shfl_xor(mx, o));
  __shared__ float redm[4], reds[4];
  if (lane == 0) redm[wave] = mx;
  __syncthreads();
  mx = fmaxf(fmaxf(redm[0], redm[1]), fmaxf(redm[2], redm[3]));

  float e[8];
  float s = 0.f;
#pragma unroll
  for (int j = 0; j < 8; ++j) {
    e[j] = mi[j] ? __expf(x[j] - mx) : 0.f;
    s += e[j];
  }
#pragma unroll
  for (int o = 32; o >= 1; o >>= 1) s += __shfl_xor(s, o);
  if (lane == 0) reds[wave] = s;
  __syncthreads();
  s = reds[0] + reds[1] + reds[2] + reds[3];
  const float inv = 1.f / s;
  f16x8 o8;
#pragma unroll
  for (int j = 0; j < 8; ++j) o8[j] = (f16)(e[j] * inv);
  ((f16x8*)p)[tid] = o8;
}

// ---------------- [B][S][E] -> [B][E][S] transpose (f16, vectorized) ----------------
__global__ __launch_bounds__(256) void transpose_bse(const f16* __restrict__ in,
                                                     f16* __restrict__ out) {
  __shared__ f16 t[64][66];
  const long b = blockIdx.z;
  const f16* ip = in + b * (long)SS * EE;
  f16* op = out + b * (long)EE * SS;
  const int e0 = blockIdx.x * 64, s0 = blockIdx.y * 64;
  const int r = threadIdx.x >> 3, c = threadIdx.x & 7;  // r 0..31, c 0..7
  *(f16x8*)&t[r][c * 8] = *(const f16x8*)&ip[(long)(s0 + r) * EE + e0 + c * 8];
  *(f16x8*)&t[r + 32][c * 8] = *(const f16x8*)&ip[(long)(s0 + r + 32) * EE + e0 + c * 8];
  __syncthreads();
  f16x8 v0, v1;
#pragma unroll
  for (int j = 0; j < 8; ++j) v0[j] = t[c * 8 + j][r];
#pragma unroll
  for (int j = 0; j < 8; ++j) v1[j] = t[c * 8 + j][r + 32];
  *(f16x8*)&op[(long)(e0 + r) * SS + s0 + c * 8] = v0;
  *(f16x8*)&op[(long)(e0 + r + 32) * SS + s0 + c * 8] = v1;
}

extern "C" void kernel_launch(void* const* d_in, const int* in_sizes, int n_in,
                              void* d_out, int out_size, void* d_ws, size_t ws_size,
                              hipStream_t stream) {
  const float* V = (const float*)d_in[0];    // values
  const float* Kin = (const float*)d_in[1];  // keys
  const float* Q = (const float*)d_in[2];    // query
  const int* mask = (const int*)d_in[3];     // [B,1,S] int32
  const float* W = (const float*)d_in[4];    // [E,E]
  const float* bias = (const float*)d_in[5]; // [E]
  float* out = (float*)d_out;

  const long NE = (long)BB * SS * EE;  // 8388608
  f16* Qh = (f16*)d_ws;                // NE
  f16* Kh = Qh + NE;                   // NE
  f16* Vh = Kh + NE;                   // NE (reused as VWt after transpose)
  f16* Wh = Vh + NE;                   // EE*EE
  f16* VW = Wh + (long)EE * EE;        // NE
  f16* P = VW + NE;                    // 2*NE (B*S*S)
  f16* VWt = Vh;

  const size_t LDSB = 131072;
  hipFuncSetAttribute((const void*)gemm256<0>,
                      hipFuncAttributeMaxDynamicSharedMemorySize, LDSB);
  hipFuncSetAttribute((const void*)gemm256<1>,
                      hipFuncAttributeMaxDynamicSharedMemorySize, LDSB);

  cvt3<<<dim3(4096, 3), 256, 0, stream>>>(Q, Kin, V, Qh, Kh, Vh);
  cvt_f32_f16<<<512, 256, 0, stream>>>(W, Wh, (EE * EE) / 8);

  // VW = V @ W^T : [B*S, E], K = E
  gemm256<0><<<dim3(EE / 256, (BB * SS) / 256, 1), 512, LDSB, stream>>>(
      Vh, Wh, VW, nullptr, EE, EE, 1.0f, 0, 0, 0);

  // VWt[b][e][s] = VW[b][s][e]
  transpose_bse<<<dim3(EE / 64, SS / 64, BB), 256, 0, stream>>>(VW, VWt);

  // scores = Q K^T / sqrt(E) : per-batch [S, S], K = E
  gemm256<0><<<dim3(SS / 256, SS / 256, BB), 512, LDSB, stream>>>(
      Qh, Kh, P, nullptr, EE, SS, 1.0f / 32.0f,
      (long)SS * EE, (long)SS * EE, (long)SS * SS);

  // P = softmax(mask(scores)) in place
  softmax_mask<<<BB * SS, 256, 0, stream>>>(P, mask);

  // out = P @ VW + b : per-batch [S, E], K = S
  gemm256<1><<<dim3(EE / 256, SS / 256, BB), 512, LDSB, stream>>>(
      P, VWt, out, bias, SS, EE, 1.0f,
      (long)SS * SS, (long)EE * SS, (long)SS * EE);
}

// Round 4
// 140.006 us; speedup vs baseline: 1.3394x; 1.2432x over previous
//
#include <hip/hip_runtime.h>

#define BB 4
#define SS 2048
#define EE 1024

typedef _Float16 f16;
typedef _Float16 f16x8 __attribute__((ext_vector_type(8)));
typedef float f32x4 __attribute__((ext_vector_type(4)));

typedef const __attribute__((address_space(1))) void* gas_ptr;
typedef __attribute__((address_space(3))) void* las_ptr;

__device__ __forceinline__ void gl_lds16(const void* g, void* l) {
  __builtin_amdgcn_global_load_lds((gas_ptr)g, (las_ptr)l, 16, 0, 0);
}

#define BAR() __builtin_amdgcn_s_barrier()
#define PRIO1() __builtin_amdgcn_s_setprio(1)
#define PRIO0() __builtin_amdgcn_s_setprio(0)
#define WAITV8() asm volatile("s_waitcnt vmcnt(8)" ::: "memory")
#define WAITV6() asm volatile("s_waitcnt vmcnt(6)" ::: "memory")
#define WAITV4() asm volatile("s_waitcnt vmcnt(4)" ::: "memory")
#define WAITV0() asm volatile("s_waitcnt vmcnt(0)" ::: "memory")

// ---------------- fused converts + rowsum zero ----------------
// y<3: Q/K/V f32->f16 (4096 blocks each). y==3: x<512 W cvt; x==512 zero rowsum.
__global__ __launch_bounds__(256) void cvt4(const float* __restrict__ x0,
                                            const float* __restrict__ x1,
                                            const float* __restrict__ x2,
                                            const float* __restrict__ x3,
                                            f16* __restrict__ o0, f16* __restrict__ o1,
                                            f16* __restrict__ o2, f16* __restrict__ o3,
                                            float* __restrict__ rowsum) {
  const int y = blockIdx.y;
  if (y == 3) {
    if (blockIdx.x == 512) {
      // zero rowsum[B*S] = 8192 floats
      float4 z = {0.f, 0.f, 0.f, 0.f};
#pragma unroll
      for (int r = 0; r < 8; ++r)
        ((float4*)rowsum)[threadIdx.x + r * 256] = z;
      return;
    }
    if (blockIdx.x >= 512) return;
    long i = (long)blockIdx.x * 256 + threadIdx.x;
    float4 v0 = ((const float4*)x3)[i * 2];
    float4 v1 = ((const float4*)x3)[i * 2 + 1];
    f16x8 o;
    o[0] = (f16)v0.x; o[1] = (f16)v0.y; o[2] = (f16)v0.z; o[3] = (f16)v0.w;
    o[4] = (f16)v1.x; o[5] = (f16)v1.y; o[6] = (f16)v1.z; o[7] = (f16)v1.w;
    ((f16x8*)o3)[i] = o;
    return;
  }
  const float* in = (y == 0) ? x0 : (y == 1) ? x1 : x2;
  f16* out = (y == 0) ? o0 : (y == 1) ? o1 : o2;
  long i = (long)blockIdx.x * 256 + threadIdx.x;
  float4 v0 = ((const float4*)in)[i * 2];
  float4 v1 = ((const float4*)in)[i * 2 + 1];
  f16x8 o;
  o[0] = (f16)v0.x; o[1] = (f16)v0.y; o[2] = (f16)v0.z; o[3] = (f16)v0.w;
  o[4] = (f16)v1.x; o[5] = (f16)v1.y; o[6] = (f16)v1.z; o[7] = (f16)v1.w;
  ((f16x8*)out)[i] = o;
}

// ---------------- shared GEMM helpers ----------------
// Swizzle: 16B-slot ^= (row&7) on global SOURCE (gload_lds dest linear) and on
// ds_read address. stage64: 64 rows x 64 cols per call, 1x16B per thread (512).
__device__ __forceinline__ void stage64(const f16* g, long K, f16* l, int h, int t) {
  int rr = t >> 3, sp = t & 7;
  int row = h * 64 + rr;
  int sl = sp ^ (rr & 7);
  gl_lds16(g + (long)row * K + (sl << 3), (char*)l + ((row << 6) + (sp << 3)) * 2);
}

__device__ __forceinline__ void read_a(f16x8 (&d)[4][2], const f16* base, int q,
                                       int wm, int l15, int l4) {
#pragma unroll
  for (int mf = 0; mf < 4; ++mf)
#pragma unroll
    for (int kk = 0; kk < 2; ++kk) {
      int row = wm * 128 + (q * 4 + mf) * 16 + l15;
      int sl = kk * 4 + l4;
      d[mf][kk] = *(const f16x8*)(base + row * 64 + ((sl ^ (row & 7)) << 3));
    }
}

__device__ __forceinline__ void read_b2(f16x8 (&d)[2][2], const f16* base, int nh,
                                        int wn, int l15, int l4) {
#pragma unroll
  for (int nf = 0; nf < 2; ++nf)
#pragma unroll
    for (int kk = 0; kk < 2; ++kk) {
      int row = wn * 64 + (nh * 2 + nf) * 16 + l15;
      int sl = kk * 4 + l4;
      d[nf][kk] = *(const f16x8*)(base + row * 64 + ((sl ^ (row & 7)) << 3));
    }
}

__device__ __forceinline__ void read_b1(f16x8 (&d)[2], const f16* base, int f,
                                        int wn, int l15, int l4) {
#pragma unroll
  for (int kk = 0; kk < 2; ++kk) {
    int row = wn * 32 + f * 16 + l15;
    int sl = kk * 4 + l4;
    d[kk] = *(const f16x8*)(base + row * 64 + ((sl ^ (row & 7)) << 3));
  }
}

// ================= 256x256 kernel (QK^T), EPI=2 epilogue =================
// P' = mask ? exp(acc*scale) : 0 (f16), rowsum += row-partials (atomic).
__device__ __forceinline__ void mfma_q(f32x4 (&acc)[8][4], const f16x8 (&Af)[4][2],
                                       const f16x8 (&Bf)[2][2], int q, int nh) {
#pragma unroll
  for (int mf = 0; mf < 4; ++mf)
#pragma unroll
    for (int nf = 0; nf < 2; ++nf)
#pragma unroll
      for (int kk = 0; kk < 2; ++kk)
        acc[q * 4 + mf][nh * 2 + nf] = __builtin_amdgcn_mfma_f32_16x16x32_f16(
            Af[mf][kk], Bf[nf][kk], acc[q * 4 + mf][nh * 2 + nf], 0, 0, 0);
}

__global__ __launch_bounds__(512, 1) void gemm256_qk(
    const f16* __restrict__ A, const f16* __restrict__ Bm, f16* __restrict__ C,
    const int* __restrict__ mask, float* __restrict__ rowsum,
    int K, int N, float scale, long sAb, long sBb, long sCb) {
  extern __shared__ f16 lds[];
  f16* As0 = lds;
  f16* As1 = lds + 16384;
  f16* Bs0 = lds + 32768;
  f16* Bs1 = lds + 49152;
  const int tid = threadIdx.x;
  const int lane = tid & 63, wv = tid >> 6;
  const int wm = wv >> 2, wn = wv & 3;
  const int l15 = lane & 15, l4 = lane >> 4;
  const long m0 = (long)blockIdx.y * 256;
  const long n0 = (long)blockIdx.x * 256;
  const f16* Ag = A + sAb * blockIdx.z + m0 * K;
  const f16* Bg = Bm + sBb * blockIdx.z + n0 * K;

  f32x4 acc[8][4] = {};
  f16x8 a[4][2], b[2][2], b2[2][2];

  const int NT = K >> 6;
  const int NIT = NT >> 1;

#pragma unroll
  for (int h = 0; h < 4; ++h) stage64(Bg, K, Bs0, h, tid);
#pragma unroll
  for (int h = 0; h < 4; ++h) stage64(Ag, K, As0, h, tid);
#pragma unroll
  for (int h = 0; h < 4; ++h) stage64(Bg + 64, K, Bs1, h, tid);
#pragma unroll
  for (int h = 0; h < 4; ++h) stage64(Ag + 64, K, As1, h, tid);
  WAITV8();
  BAR();

  for (int i = 0; i < NIT; ++i) {
    int t2 = 2 * i + 2, t3 = 2 * i + 3;
    long k2 = (long)((t2 < NT) ? t2 : NT - 1) << 6;
    long k3 = (long)((t3 < NT) ? t3 : NT - 1) << 6;
    read_a(a, As0, 0, wm, l15, l4);
    read_b2(b, Bs0, 0, wn, l15, l4);
    BAR(); PRIO1(); mfma_q(acc, a, b, 0, 0); PRIO0(); BAR();
    read_b2(b2, Bs0, 1, wn, l15, l4);
    BAR(); PRIO1(); mfma_q(acc, a, b2, 0, 1); PRIO0(); BAR();
    read_a(a, As0, 1, wm, l15, l4);
    stage64(Bg + k2, K, Bs0, 0, tid); stage64(Bg + k2, K, Bs0, 1, tid);
    BAR(); PRIO1(); mfma_q(acc, a, b2, 1, 1); PRIO0(); BAR();
    stage64(Bg + k2, K, Bs0, 2, tid); stage64(Bg + k2, K, Bs0, 3, tid);
    BAR(); PRIO1(); mfma_q(acc, a, b, 1, 0); PRIO0();
    WAITV4();
    BAR();
    read_a(a, As1, 0, wm, l15, l4);
    read_b2(b, Bs1, 0, wn, l15, l4);
    stage64(Ag + k2, K, As0, 0, tid); stage64(Ag + k2, K, As0, 1, tid);
    BAR(); PRIO1(); mfma_q(acc, a, b, 0, 0); PRIO0(); BAR();
    read_b2(b2, Bs1, 1, wn, l15, l4);
    stage64(Ag + k2, K, As0, 2, tid); stage64(Ag + k2, K, As0, 3, tid);
    BAR(); PRIO1(); mfma_q(acc, a, b2, 0, 1); PRIO0(); BAR();
    read_a(a, As1, 1, wm, l15, l4);
    stage64(Bg + k3, K, Bs1, 0, tid); stage64(Bg + k3, K, Bs1, 1, tid);
    BAR(); PRIO1(); mfma_q(acc, a, b2, 1, 1); PRIO0(); BAR();
    stage64(Bg + k3, K, Bs1, 2, tid); stage64(Bg + k3, K, Bs1, 3, tid);
    stage64(Ag + k3, K, As1, 0, tid); stage64(Ag + k3, K, As1, 1, tid);
    stage64(Ag + k3, K, As1, 2, tid); stage64(Ag + k3, K, As1, 3, tid);
    BAR(); PRIO1(); mfma_q(acc, a, b, 1, 0); PRIO0();
    WAITV8();
    BAR();
  }
  WAITV0();

  const long crow = m0 + wm * 128 + l4 * 4;
  const long ccol = n0 + wn * 64 + l15;
  f16* Co = C + sCb * blockIdx.z;
  const int* mk = mask + (blockIdx.z << 11);
  float* rs = rowsum + (blockIdx.z << 11);
  int mv[4];
#pragma unroll
  for (int nf = 0; nf < 4; ++nf) mv[nf] = mk[ccol + nf * 16];
#pragma unroll
  for (int mf = 0; mf < 8; ++mf)
#pragma unroll
    for (int j = 0; j < 4; ++j) {
      float rp = 0.f;
#pragma unroll
      for (int nf = 0; nf < 4; ++nf) {
        float p = mv[nf] ? __expf(acc[mf][nf][j] * scale) : 0.f;
        Co[(crow + mf * 16 + j) * N + ccol + nf * 16] = (f16)p;
        rp += p;
      }
      rp += __shfl_xor(rp, 1); rp += __shfl_xor(rp, 2);
      rp += __shfl_xor(rp, 4); rp += __shfl_xor(rp, 8);
      if (l15 == 0) atomicAdd(&rs[crow + mf * 16 + j], rp);
    }
}

// ================= 256x128 kernel, EPI 0 (f16) / 3 (f32 /rowsum + bias) ====
// 8 waves 2M x 4N: wave = 128 rows x 32 cols, acc[8][2]. 6 loads/K-tile.
__device__ __forceinline__ void mfma_n(f32x4 (&acc)[8][2], const f16x8 (&Af)[4][2],
                                       const f16x8 (&Bf)[2], int q, int f) {
#pragma unroll
  for (int mf = 0; mf < 4; ++mf)
#pragma unroll
    for (int kk = 0; kk < 2; ++kk)
      acc[q * 4 + mf][f] = __builtin_amdgcn_mfma_f32_16x16x32_f16(
          Af[mf][kk], Bf[kk], acc[q * 4 + mf][f], 0, 0, 0);
}

template <int EPI>
__global__ __launch_bounds__(512, 1) void gemm_n128(
    const f16* __restrict__ A, const f16* __restrict__ Bm, void* __restrict__ C,
    const float* __restrict__ bias, const float* __restrict__ rowsum,
    int K, int N, float scale, long sAb, long sBb, long sCb) {
  extern __shared__ f16 lds[];
  f16* As0 = lds;            // 256x64
  f16* As1 = lds + 16384;
  f16* Bs0 = lds + 32768;    // 128x64
  f16* Bs1 = lds + 40960;
  const int tid = threadIdx.x;
  const int lane = tid & 63, wv = tid >> 6;
  const int wm = wv >> 2, wn = wv & 3;
  const int l15 = lane & 15, l4 = lane >> 4;
  const long m0 = (long)blockIdx.y * 256;
  const long n0 = (long)blockIdx.x * 128;
  const f16* Ag = A + sAb * blockIdx.z + m0 * K;
  const f16* Bg = Bm + sBb * blockIdx.z + n0 * K;

  f32x4 acc[8][2] = {};
  f16x8 a[4][2], b[2], b2[2];

  const int NT = K >> 6;
  const int NIT = NT >> 1;

  // prologue: B0(2) A0(4) B1(2) A1(4)
  stage64(Bg, K, Bs0, 0, tid); stage64(Bg, K, Bs0, 1, tid);
#pragma unroll
  for (int h = 0; h < 4; ++h) stage64(Ag, K, As0, h, tid);
  stage64(Bg + 64, K, Bs1, 0, tid); stage64(Bg + 64, K, Bs1, 1, tid);
#pragma unroll
  for (int h = 0; h < 4; ++h) stage64(Ag + 64, K, As1, h, tid);
  WAITV6();  // tile-a's 6 done; tile-b's 6 in flight
  BAR();

  for (int i = 0; i < NIT; ++i) {
    int t2 = 2 * i + 2, t3 = 2 * i + 3;
    long k2 = (long)((t2 < NT) ? t2 : NT - 1) << 6;
    long k3 = (long)((t3 < NT) ? t3 : NT - 1) << 6;
    // tile a (buf0)
    read_a(a, As0, 0, wm, l15, l4);
    read_b1(b, Bs0, 0, wn, l15, l4);
    BAR(); PRIO1(); mfma_n(acc, a, b, 0, 0); PRIO0(); BAR();
    read_b1(b2, Bs0, 1, wn, l15, l4);
    BAR(); PRIO1(); mfma_n(acc, a, b2, 0, 1); PRIO0(); BAR();
    read_a(a, As0, 1, wm, l15, l4);
    stage64(Bg + k2, K, Bs0, 0, tid); stage64(Bg + k2, K, Bs0, 1, tid);  // B free after P1
    BAR(); PRIO1(); mfma_n(acc, a, b2, 1, 1); PRIO0(); BAR();
#pragma unroll
    for (int h = 0; h < 4; ++h) stage64(Ag + k2, K, As0, h, tid);        // A free after P2
    BAR(); PRIO1(); mfma_n(acc, a, b, 1, 0); PRIO0();
    WAITV6();  // tile-b's 6 done; k2's 6 in flight
    BAR();
    // tile b (buf1)
    read_a(a, As1, 0, wm, l15, l4);
    read_b1(b, Bs1, 0, wn, l15, l4);
    BAR(); PRIO1(); mfma_n(acc, a, b, 0, 0); PRIO0(); BAR();
    read_b1(b2, Bs1, 1, wn, l15, l4);
    BAR(); PRIO1(); mfma_n(acc, a, b2, 0, 1); PRIO0(); BAR();
    read_a(a, As1, 1, wm, l15, l4);
    stage64(Bg + k3, K, Bs1, 0, tid); stage64(Bg + k3, K, Bs1, 1, tid);
    BAR(); PRIO1(); mfma_n(acc, a, b2, 1, 1); PRIO0(); BAR();
#pragma unroll
    for (int h = 0; h < 4; ++h) stage64(Ag + k3, K, As1, h, tid);
    BAR(); PRIO1(); mfma_n(acc, a, b, 1, 0); PRIO0();
    WAITV6();  // k2's 6 done -> next tile-a readable
    BAR();
  }
  WAITV0();

  const long crow = m0 + wm * 128 + l4 * 4;
  const long ccol = n0 + wn * 32 + l15;
  if (EPI == 0) {
    f16* Co = (f16*)C + sCb * blockIdx.z;
#pragma unroll
    for (int mf = 0; mf < 8; ++mf)
#pragma unroll
      for (int nf = 0; nf < 2; ++nf)
#pragma unroll
        for (int j = 0; j < 4; ++j)
          Co[(crow + mf * 16 + j) * N + ccol + nf * 16] = (f16)(acc[mf][nf][j] * scale);
  } else {
    float* Co = (float*)C + sCb * blockIdx.z;
    const float* rs = rowsum + (blockIdx.z << 11);
    float bv[2];
#pragma unroll
    for (int nf = 0; nf < 2; ++nf) bv[nf] = bias[ccol + nf * 16];
#pragma unroll
    for (int mf = 0; mf < 8; ++mf)
#pragma unroll
      for (int j = 0; j < 4; ++j) {
        float inv = 1.f / rs[crow + mf * 16 + j];
#pragma unroll
        for (int nf = 0; nf < 2; ++nf)
          Co[(crow + mf * 16 + j) * N + ccol + nf * 16] =
              acc[mf][nf][j] * inv + bv[nf];
      }
  }
}

extern "C" void kernel_launch(void* const* d_in, const int* in_sizes, int n_in,
                              void* d_out, int out_size, void* d_ws, size_t ws_size,
                              hipStream_t stream) {
  const float* V = (const float*)d_in[0];
  const float* Kin = (const float*)d_in[1];
  const float* Q = (const float*)d_in[2];
  const int* mask = (const int*)d_in[3];
  const float* W = (const float*)d_in[4];
  const float* bias = (const float*)d_in[5];
  float* out = (float*)d_out;

  const long NE = (long)BB * SS * EE;  // 8388608
  f16* Qh = (f16*)d_ws;                  // NE
  f16* Kh = Qh + NE;                     // NE
  f16* Vh = Kh + NE;                     // NE
  f16* Wh = Vh + NE;                     // EE*EE
  f16* VWt = Wh + (long)EE * EE;         // NE  ([B][E][S])
  f16* P = VWt + NE;                     // 2*NE ([B][S][S] unnormalized exp)
  float* rowsum = (float*)(P + (long)BB * SS * SS);  // B*S f32

  const size_t LDS_QK = 131072, LDS_N = 98304;
  hipFuncSetAttribute((const void*)gemm256_qk,
                      hipFuncAttributeMaxDynamicSharedMemorySize, LDS_QK);
  hipFuncSetAttribute((const void*)gemm_n128<0>,
                      hipFuncAttributeMaxDynamicSharedMemorySize, LDS_N);
  hipFuncSetAttribute((const void*)gemm_n128<3>,
                      hipFuncAttributeMaxDynamicSharedMemorySize, LDS_N);

  // converts + rowsum zero
  cvt4<<<dim3(4096, 4), 256, 0, stream>>>(Q, Kin, V, W, Qh, Kh, Vh, Wh, rowsum);

  // P' = exp(mask(Q K^T / 32)), rowsum accumulated
  gemm256_qk<<<dim3(SS / 256, SS / 256, BB), 512, LDS_QK, stream>>>(
      Qh, Kh, P, mask, rowsum, EE, SS, 1.0f / 32.0f,
      (long)SS * EE, (long)SS * EE, (long)SS * SS);

  // VWt = W @ V^T : [E, S] per batch (A = W [E,E], Bm = V [S,E])
  gemm_n128<0><<<dim3(SS / 128, EE / 256, BB), 512, LDS_N, stream>>>(
      Wh, Vh, VWt, nullptr, nullptr, EE, SS, 1.0f,
      0, (long)SS * EE, (long)EE * SS);

  // out = (P' @ VWt) / rowsum + bias
  gemm_n128<3><<<dim3(EE / 128, SS / 256, BB), 512, LDS_N, stream>>>(
      P, VWt, out, bias, rowsum, SS, EE, 1.0f,
      (long)SS * SS, (long)EE * SS, (long)SS * EE);
}

// Round 5
// 125.147 us; speedup vs baseline: 1.4984x; 1.1187x over previous
//
#include <hip/hip_runtime.h>

#define BB 4
#define SS 2048
#define EE 1024

typedef _Float16 f16;
typedef _Float16 f16x4 __attribute__((ext_vector_type(4)));
typedef _Float16 f16x8 __attribute__((ext_vector_type(8)));
typedef float f32x4 __attribute__((ext_vector_type(4)));

typedef const __attribute__((address_space(1))) void* gas_ptr;
typedef __attribute__((address_space(3))) void* las_ptr;

__device__ __forceinline__ void gl_lds16(const void* g, void* l) {
  __builtin_amdgcn_global_load_lds((gas_ptr)g, (las_ptr)l, 16, 0, 0);
}

#define BAR() __builtin_amdgcn_s_barrier()
#define PRIO1() __builtin_amdgcn_s_setprio(1)
#define PRIO0() __builtin_amdgcn_s_setprio(0)
#define WAITV6() asm volatile("s_waitcnt vmcnt(6)" ::: "memory")
#define WAITV0() asm volatile("s_waitcnt vmcnt(0)" ::: "memory")

// ---------- prep: per-batch mask prefix-scan + pad-row zeroing ----------
__global__ __launch_bounds__(256) void prep(const int* __restrict__ mask,
                                            int* __restrict__ pos,
                                            int2* __restrict__ cnt,
                                            f16* __restrict__ Kc,
                                            f16* __restrict__ Vc) {
  const int b = blockIdx.x, t = threadIdx.x;
  const int* mb = mask + b * SS;
  int4 a0 = ((const int4*)mb)[t * 2];
  int4 a1 = ((const int4*)mb)[t * 2 + 1];
  int m[8] = {a0.x, a0.y, a0.z, a0.w, a1.x, a1.y, a1.z, a1.w};
  int tot = 0;
#pragma unroll
  for (int j = 0; j < 8; ++j) tot += m[j];
  __shared__ int sc[256];
  sc[t] = tot;
  __syncthreads();
  for (int off = 1; off < 256; off <<= 1) {
    int v = (t >= off) ? sc[t - off] : 0;
    __syncthreads();
    sc[t] += v;
    __syncthreads();
  }
  const int count = sc[255];
  const int padded = (count + 127) & ~127;
  int run = sc[t] - tot;  // exclusive prefix
#pragma unroll
  for (int j = 0; j < 8; ++j) {
    pos[b * SS + t * 8 + j] = run;
    run += m[j];
  }
  if (t == 0) cnt[b] = make_int2(count, padded);
  // zero pad rows [count, padded) of Kc, Vc
  const int nz = (padded - count) * 128;  // f16x8 units per array
  f16x8 z = {};
  for (int i = t; i < nz; i += 256) {
    int r = count + (i >> 7), cc = i & 127;
    ((f16x8*)(Kc + ((long)b * SS + r) * EE))[cc] = z;
    ((f16x8*)(Vc + ((long)b * SS + r) * EE))[cc] = z;
  }
}

// ---------- gather: masked K/V rows, f32 -> f16 compacted ----------
__global__ __launch_bounds__(256) void gather(const float* __restrict__ K,
                                              const float* __restrict__ V,
                                              const int* __restrict__ mask,
                                              const int* __restrict__ pos,
                                              f16* __restrict__ Kc,
                                              f16* __restrict__ Vc) {
  const int s = blockIdx.x, b = blockIdx.y, t = threadIdx.x;
  if (!mask[b * SS + s]) return;
  const int p = pos[b * SS + s];
  float4 kv = ((const float4*)(K + ((long)b * SS + s) * EE))[t];
  float4 vv = ((const float4*)(V + ((long)b * SS + s) * EE))[t];
  f16x4 ko, vo;
  ko[0] = (f16)kv.x; ko[1] = (f16)kv.y; ko[2] = (f16)kv.z; ko[3] = (f16)kv.w;
  vo[0] = (f16)vv.x; vo[1] = (f16)vv.y; vo[2] = (f16)vv.z; vo[3] = (f16)vv.w;
  ((f16x4*)(Kc + ((long)b * SS + p) * EE))[t] = ko;
  ((f16x4*)(Vc + ((long)b * SS + p) * EE))[t] = vo;
}

// ---------- cvt: Q + W f32->f16, rowsum zero ----------
__global__ __launch_bounds__(256) void cvtQW(const float* __restrict__ Q,
                                             const float* __restrict__ W,
                                             f16* __restrict__ Qh,
                                             f16* __restrict__ Wh,
                                             float* __restrict__ rowsum) {
  const int x = blockIdx.x;
  if (x == 4608) {
    float4 z = {0.f, 0.f, 0.f, 0.f};
#pragma unroll
    for (int r = 0; r < 8; ++r)
      ((float4*)rowsum)[threadIdx.x + r * 256] = z;
    return;
  }
  const float* in = (x < 4096) ? Q : W;
  f16* out = (x < 4096) ? Qh : Wh;
  long i = (long)(x < 4096 ? x : x - 4096) * 256 + threadIdx.x;
  float4 v0 = ((const float4*)in)[i * 2];
  float4 v1 = ((const float4*)in)[i * 2 + 1];
  f16x8 o;
  o[0] = (f16)v0.x; o[1] = (f16)v0.y; o[2] = (f16)v0.z; o[3] = (f16)v0.w;
  o[4] = (f16)v1.x; o[5] = (f16)v1.y; o[6] = (f16)v1.z; o[7] = (f16)v1.w;
  ((f16x8*)out)[i] = o;
}

// ---------- shared 256x128 8-phase GEMM core ----------
// Swizzle: 16B-slot ^= (row&7) on global SOURCE and ds_read addr.
__device__ __forceinline__ void stage64(const f16* g, long K, f16* l, int h, int t) {
  int rr = t >> 3, sp = t & 7;
  int row = h * 64 + rr;
  int sl = sp ^ (rr & 7);
  gl_lds16(g + (long)row * K + (sl << 3), (char*)l + ((row << 6) + (sp << 3)) * 2);
}

__device__ __forceinline__ void read_a(f16x8 (&d)[4][2], const f16* base, int q,
                                       int wm, int l15, int l4) {
#pragma unroll
  for (int mf = 0; mf < 4; ++mf)
#pragma unroll
    for (int kk = 0; kk < 2; ++kk) {
      int row = wm * 128 + (q * 4 + mf) * 16 + l15;
      int sl = kk * 4 + l4;
      d[mf][kk] = *(const f16x8*)(base + row * 64 + ((sl ^ (row & 7)) << 3));
    }
}

__device__ __forceinline__ void read_b1(f16x8 (&d)[2], const f16* base, int f,
                                        int wn, int l15, int l4) {
#pragma unroll
  for (int kk = 0; kk < 2; ++kk) {
    int row = wn * 32 + f * 16 + l15;
    int sl = kk * 4 + l4;
    d[kk] = *(const f16x8*)(base + row * 64 + ((sl ^ (row & 7)) << 3));
  }
}

__device__ __forceinline__ void mfma_n(f32x4 (&acc)[8][2], const f16x8 (&Af)[4][2],
                                       const f16x8 (&Bf)[2], int q, int f) {
#pragma unroll
  for (int mf = 0; mf < 4; ++mf)
#pragma unroll
    for (int kk = 0; kk < 2; ++kk)
      acc[q * 4 + mf][f] = __builtin_amdgcn_mfma_f32_16x16x32_f16(
          Af[mf][kk], Bf[kk], acc[q * 4 + mf][f], 0, 0, 0);
}

// 8 waves 2M x 4N; 6 loads/K-tile; counted vmcnt(6) gates (R4-verified).
__device__ __forceinline__ void n128_core(f32x4 (&acc)[8][2], const f16* Ag,
                                          const f16* Bg, long L, int NT,
                                          f16* lds, int tid, int wm, int wn,
                                          int l15, int l4) {
  f16* As0 = lds;
  f16* As1 = lds + 16384;
  f16* Bs0 = lds + 32768;
  f16* Bs1 = lds + 40960;
  f16x8 a[4][2], b[2], b2[2];
  const int NIT = NT >> 1;

  stage64(Bg, L, Bs0, 0, tid); stage64(Bg, L, Bs0, 1, tid);
#pragma unroll
  for (int h = 0; h < 4; ++h) stage64(Ag, L, As0, h, tid);
  stage64(Bg + 64, L, Bs1, 0, tid); stage64(Bg + 64, L, Bs1, 1, tid);
#pragma unroll
  for (int h = 0; h < 4; ++h) stage64(Ag + 64, L, As1, h, tid);
  WAITV6();
  BAR();

  for (int i = 0; i < NIT; ++i) {
    int t2 = 2 * i + 2, t3 = 2 * i + 3;
    long k2 = (long)((t2 < NT) ? t2 : NT - 1) << 6;
    long k3 = (long)((t3 < NT) ? t3 : NT - 1) << 6;
    read_a(a, As0, 0, wm, l15, l4);
    read_b1(b, Bs0, 0, wn, l15, l4);
    BAR(); PRIO1(); mfma_n(acc, a, b, 0, 0); PRIO0(); BAR();
    read_b1(b2, Bs0, 1, wn, l15, l4);
    BAR(); PRIO1(); mfma_n(acc, a, b2, 0, 1); PRIO0(); BAR();
    read_a(a, As0, 1, wm, l15, l4);
    stage64(Bg + k2, L, Bs0, 0, tid); stage64(Bg + k2, L, Bs0, 1, tid);
    BAR(); PRIO1(); mfma_n(acc, a, b2, 1, 1); PRIO0(); BAR();
#pragma unroll
    for (int h = 0; h < 4; ++h) stage64(Ag + k2, L, As0, h, tid);
    BAR(); PRIO1(); mfma_n(acc, a, b, 1, 0); PRIO0();
    WAITV6();
    BAR();
    read_a(a, As1, 0, wm, l15, l4);
    read_b1(b, Bs1, 0, wn, l15, l4);
    BAR(); PRIO1(); mfma_n(acc, a, b, 0, 0); PRIO0(); BAR();
    read_b1(b2, Bs1, 1, wn, l15, l4);
    BAR(); PRIO1(); mfma_n(acc, a, b2, 0, 1); PRIO0(); BAR();
    read_a(a, As1, 1, wm, l15, l4);
    stage64(Bg + k3, L, Bs1, 0, tid); stage64(Bg + k3, L, Bs1, 1, tid);
    BAR(); PRIO1(); mfma_n(acc, a, b2, 1, 1); PRIO0(); BAR();
#pragma unroll
    for (int h = 0; h < 4; ++h) stage64(Ag + k3, L, As1, h, tid);
    BAR(); PRIO1(); mfma_n(acc, a, b, 1, 0); PRIO0();
    WAITV6();
    BAR();
  }
  WAITV0();
}

// ---------- QK^T: P' = (col<count) ? exp(acc/32) : 0, rowsum atomic ----------
__global__ __launch_bounds__(512, 1) void qk128(const f16* __restrict__ Qh,
                                                const f16* __restrict__ Kc,
                                                f16* __restrict__ P,
                                                float* __restrict__ rowsum,
                                                const int2* __restrict__ cnt) {
  extern __shared__ f16 lds[];
  // XCD swizzle decode, grid (16,8,4): y-row per XCD
  int d = blockIdx.x + blockIdx.y * 16 + blockIdx.z * 128;
  int c = d & 7, j = d >> 3;
  const int bx = j & 15, by = c, bz = j >> 4;
  int2 cc = cnt[bz];
  const int count = cc.x, padded = cc.y;
  const long n0 = (long)bx * 128;
  if (n0 >= padded) return;
  const long m0 = (long)by * 256;
  const int tid = threadIdx.x;
  const int lane = tid & 63, wv = tid >> 6;
  const int wm = wv >> 2, wn = wv & 3;
  const int l15 = lane & 15, l4 = lane >> 4;
  const f16* Ag = Qh + (long)bz * SS * EE + m0 * EE;
  const f16* Bg = Kc + (long)bz * SS * EE + n0 * EE;

  f32x4 acc[8][2] = {};
  n128_core(acc, Ag, Bg, EE, EE >> 6, lds, tid, wm, wn, l15, l4);

  const long crow = m0 + wm * 128 + l4 * 4;
  const long ccol = n0 + wn * 32 + l15;
  f16* Co = P + (long)bz * SS * SS;
  float* rs = rowsum + (bz << 11);
  const float scale = 1.0f / 32.0f;
  int mv[2];
#pragma unroll
  for (int nf = 0; nf < 2; ++nf) mv[nf] = (ccol + nf * 16) < count;
#pragma unroll
  for (int mf = 0; mf < 8; ++mf)
#pragma unroll
    for (int jj = 0; jj < 4; ++jj) {
      float rp = 0.f;
#pragma unroll
      for (int nf = 0; nf < 2; ++nf) {
        float p = mv[nf] ? __expf(acc[mf][nf][jj] * scale) : 0.f;
        Co[(crow + mf * 16 + jj) * SS + ccol + nf * 16] = (f16)p;
        rp += p;
      }
      rp += __shfl_xor(rp, 1); rp += __shfl_xor(rp, 2);
      rp += __shfl_xor(rp, 4); rp += __shfl_xor(rp, 8);
      if (l15 == 0) atomicAdd(&rs[crow + mf * 16 + jj], rp);
    }
}

// ---------- VWt: C[E][Sc] = W @ Vc^T (f16) ----------
__global__ __launch_bounds__(512, 1) void wv128(const f16* __restrict__ Wh,
                                                const f16* __restrict__ Vc,
                                                f16* __restrict__ VWt,
                                                const int2* __restrict__ cnt) {
  extern __shared__ f16 lds[];
  // chunked swizzle decode, grid (16,4,4)
  int d = blockIdx.x + blockIdx.y * 16 + blockIdx.z * 64;
  int nw = (d & 7) * 32 + (d >> 3);
  const int bx = nw & 15, by = (nw >> 4) & 3, bz = nw >> 6;
  int2 cc = cnt[bz];
  const int padded = cc.y;
  const long n0 = (long)bx * 128;
  if (n0 >= padded) return;
  const long m0 = (long)by * 256;
  const int tid = threadIdx.x;
  const int lane = tid & 63, wv = tid >> 6;
  const int wm = wv >> 2, wn = wv & 3;
  const int l15 = lane & 15, l4 = lane >> 4;
  const f16* Ag = Wh + m0 * EE;
  const f16* Bg = Vc + (long)bz * SS * EE + n0 * EE;

  f32x4 acc[8][2] = {};
  n128_core(acc, Ag, Bg, EE, EE >> 6, lds, tid, wm, wn, l15, l4);

  const long crow = m0 + wm * 128 + l4 * 4;
  const long ccol = n0 + wn * 32 + l15;
  f16* Co = VWt + (long)bz * EE * SS;
#pragma unroll
  for (int mf = 0; mf < 8; ++mf)
#pragma unroll
    for (int nf = 0; nf < 2; ++nf)
#pragma unroll
      for (int jj = 0; jj < 4; ++jj)
        Co[(crow + mf * 16 + jj) * SS + ccol + nf * 16] = (f16)acc[mf][nf][jj];
}

// ---------- PV: out = (P' @ VWt^T) / rowsum + bias (f32) ----------
__global__ __launch_bounds__(512, 1) void pv128(const f16* __restrict__ P,
                                                const f16* __restrict__ VWt,
                                                float* __restrict__ out,
                                                const float* __restrict__ bias,
                                                const float* __restrict__ rowsum,
                                                const int2* __restrict__ cnt) {
  extern __shared__ f16 lds[];
  // XCD swizzle decode, grid (8,8,4): y-row per XCD
  int d = blockIdx.x + blockIdx.y * 8 + blockIdx.z * 64;
  int c = d & 7, j = d >> 3;
  const int bx = j & 7, by = c, bz = j >> 3;
  int2 cc = cnt[bz];
  const int padded = cc.y;
  if (padded <= 0) return;  // never taken; forces cnt-load wait before staging
  const long m0 = (long)by * 256;
  const long n0 = (long)bx * 128;
  const int tid = threadIdx.x;
  const int lane = tid & 63, wv = tid >> 6;
  const int wm = wv >> 2, wn = wv & 3;
  const int l15 = lane & 15, l4 = lane >> 4;
  const f16* Ag = P + (long)bz * SS * SS + m0 * SS;
  const f16* Bg = VWt + (long)bz * EE * SS + n0 * SS;

  f32x4 acc[8][2] = {};
  n128_core(acc, Ag, Bg, SS, padded >> 6, lds, tid, wm, wn, l15, l4);

  const long crow = m0 + wm * 128 + l4 * 4;
  const long ccol = n0 + wn * 32 + l15;
  float* Co = out + (long)bz * SS * EE;
  const float* rs = rowsum + (bz << 11);
  float bv[2];
#pragma unroll
  for (int nf = 0; nf < 2; ++nf) bv[nf] = bias[ccol + nf * 16];
#pragma unroll
  for (int mf = 0; mf < 8; ++mf)
#pragma unroll
    for (int jj = 0; jj < 4; ++jj) {
      float inv = 1.f / rs[crow + mf * 16 + jj];
#pragma unroll
      for (int nf = 0; nf < 2; ++nf)
        Co[(crow + mf * 16 + jj) * EE + ccol + nf * 16] =
            acc[mf][nf][jj] * inv + bv[nf];
    }
}

extern "C" void kernel_launch(void* const* d_in, const int* in_sizes, int n_in,
                              void* d_out, int out_size, void* d_ws, size_t ws_size,
                              hipStream_t stream) {
  const float* V = (const float*)d_in[0];
  const float* Kin = (const float*)d_in[1];
  const float* Q = (const float*)d_in[2];
  const int* mask = (const int*)d_in[3];
  const float* W = (const float*)d_in[4];
  const float* bias = (const float*)d_in[5];
  float* out = (float*)d_out;

  const long NE = (long)BB * SS * EE;  // 8388608
  f16* Qh = (f16*)d_ws;                  // NE
  f16* Kc = Qh + NE;                     // NE (compacted K, f16)
  f16* Vc = Kc + NE;                     // NE (compacted V, f16)
  f16* Wh = Vc + NE;                     // EE*EE
  f16* VWt = Wh + (long)EE * EE;         // NE ([B][E][S] stride SS, cols<padded valid)
  f16* P = VWt + NE;                     // 2*NE ([B][S][S] stride SS, cols<padded valid)
  float* rowsum = (float*)(P + (long)BB * SS * SS);  // B*S
  int* pos = (int*)(rowsum + (long)BB * SS);         // B*S
  int2* cnt = (int2*)(pos + (long)BB * SS);          // B

  const size_t LDS_N = 98304;
  hipFuncSetAttribute((const void*)qk128, hipFuncAttributeMaxDynamicSharedMemorySize, LDS_N);
  hipFuncSetAttribute((const void*)wv128, hipFuncAttributeMaxDynamicSharedMemorySize, LDS_N);
  hipFuncSetAttribute((const void*)pv128, hipFuncAttributeMaxDynamicSharedMemorySize, LDS_N);

  prep<<<BB, 256, 0, stream>>>(mask, pos, cnt, Kc, Vc);
  cvtQW<<<4609, 256, 0, stream>>>(Q, W, Qh, Wh, rowsum);
  gather<<<dim3(SS, BB), 256, 0, stream>>>(Kin, V, mask, pos, Kc, Vc);

  // P' = exp(mask(Q Kc^T / 32)) on compacted cols, rowsum accumulated
  qk128<<<dim3(16, 8, BB), 512, LDS_N, stream>>>(Qh, Kc, P, rowsum, cnt);

  // VWt = W @ Vc^T : [E, Sc] per batch
  wv128<<<dim3(16, 4, BB), 512, LDS_N, stream>>>(Wh, Vc, VWt, cnt);

  // out = (P' @ VWt^T) / rowsum + bias
  pv128<<<dim3(8, 8, BB), 512, LDS_N, stream>>>(P, VWt, out, bias, rowsum, cnt);
}

// Round 6
// 109.090 us; speedup vs baseline: 1.7190x; 1.1472x over previous
//
#include <hip/hip_runtime.h>

#define BB 4
#define SS 2048
#define EE 1024

typedef _Float16 f16;
typedef _Float16 f16x4 __attribute__((ext_vector_type(4)));
typedef _Float16 f16x8 __attribute__((ext_vector_type(8)));
typedef float f32x4 __attribute__((ext_vector_type(4)));

typedef const __attribute__((address_space(1))) void* gas_ptr;
typedef __attribute__((address_space(3))) void* las_ptr;

__device__ __forceinline__ void gl_lds16(const void* g, void* l) {
  __builtin_amdgcn_global_load_lds((gas_ptr)g, (las_ptr)l, 16, 0, 0);
}

#define BAR() __builtin_amdgcn_s_barrier()
#define PRIO1() __builtin_amdgcn_s_setprio(1)
#define PRIO0() __builtin_amdgcn_s_setprio(0)
#define WAITV6() asm volatile("s_waitcnt vmcnt(6)" ::: "memory")
#define WAITV0() asm volatile("s_waitcnt vmcnt(0)" ::: "memory")

// ---------- prep: per-batch mask prefix-scan + pad-row zeroing ----------
__global__ __launch_bounds__(256) void prep(const int* __restrict__ mask,
                                            int* __restrict__ pos,
                                            int2* __restrict__ cnt,
                                            f16* __restrict__ Kc,
                                            f16* __restrict__ Vc) {
  const int b = blockIdx.x, t = threadIdx.x;
  const int* mb = mask + b * SS;
  int4 a0 = ((const int4*)mb)[t * 2];
  int4 a1 = ((const int4*)mb)[t * 2 + 1];
  int m[8] = {a0.x, a0.y, a0.z, a0.w, a1.x, a1.y, a1.z, a1.w};
  int tot = 0;
#pragma unroll
  for (int j = 0; j < 8; ++j) tot += m[j];
  __shared__ int sc[256];
  sc[t] = tot;
  __syncthreads();
  for (int off = 1; off < 256; off <<= 1) {
    int v = (t >= off) ? sc[t - off] : 0;
    __syncthreads();
    sc[t] += v;
    __syncthreads();
  }
  const int count = sc[255];
  const int padded = (count + 127) & ~127;
  int run = sc[t] - tot;  // exclusive prefix
#pragma unroll
  for (int j = 0; j < 8; ++j) {
    pos[b * SS + t * 8 + j] = run;
    run += m[j];
  }
  if (t == 0) cnt[b] = make_int2(count, padded);
  // zero pad rows [count, padded) of Kc, Vc
  const int nz = (padded - count) * 128;  // f16x8 units per array
  f16x8 z = {};
  for (int i = t; i < nz; i += 256) {
    int r = count + (i >> 7), cc = i & 127;
    ((f16x8*)(Kc + ((long)b * SS + r) * EE))[cc] = z;
    ((f16x8*)(Vc + ((long)b * SS + r) * EE))[cc] = z;
  }
}

// ---------- fused: Q/W cvt, rowsum zero, item-list build, K/V gather ----------
__global__ __launch_bounds__(256) void prep2(const float* __restrict__ Q,
                                             const float* __restrict__ W,
                                             const float* __restrict__ K,
                                             const float* __restrict__ V,
                                             const int* __restrict__ mask,
                                             const int* __restrict__ pos,
                                             const int2* __restrict__ cnt,
                                             f16* __restrict__ Qh,
                                             f16* __restrict__ Wh,
                                             f16* __restrict__ Kc,
                                             f16* __restrict__ Vc,
                                             float* __restrict__ rowsum,
                                             int* __restrict__ items,
                                             int* __restrict__ nit) {
  const int x = blockIdx.x, t = threadIdx.x;
  if (x < 4608) {  // Q cvt (x<4096) or W cvt
    const float* in = (x < 4096) ? Q : W;
    f16* out = (x < 4096) ? Qh : Wh;
    long i = (long)(x < 4096 ? x : x - 4096) * 256 + t;
    float4 v0 = ((const float4*)in)[i * 2];
    float4 v1 = ((const float4*)in)[i * 2 + 1];
    f16x8 o;
    o[0] = (f16)v0.x; o[1] = (f16)v0.y; o[2] = (f16)v0.z; o[3] = (f16)v0.w;
    o[4] = (f16)v1.x; o[5] = (f16)v1.y; o[6] = (f16)v1.z; o[7] = (f16)v1.w;
    ((f16x8*)out)[i] = o;
    return;
  }
  if (x == 4608) {  // zero rowsum[B*S]
    float4 z = {0.f, 0.f, 0.f, 0.f};
#pragma unroll
    for (int r = 0; r < 8; ++r) ((float4*)rowsum)[t + r * 256] = z;
    return;
  }
  if (x == 4609) {  // build item list: QK items (kind 0), then WV items (kind 1)
    if (t < 48) {
      int nbx[4], pre[5];
      pre[0] = 0;
#pragma unroll
      for (int z = 0; z < 4; ++z) {
        nbx[z] = cnt[z].y >> 7;
        pre[z + 1] = pre[z] + nbx[z];
      }
      if (t < 32) {
        int bz = t >> 3, by = t & 7;
        int base = 8 * pre[bz] + by * nbx[bz];
        for (int bx = 0; bx < nbx[bz]; ++bx)
          items[base + bx] = bx | (by << 8) | (bz << 16);
      } else {
        int p = t - 32, bz = p >> 2, by = p & 3;
        int base = 8 * pre[4] + 4 * pre[bz] + by * nbx[bz];
        for (int bx = 0; bx < nbx[bz]; ++bx)
          items[base + bx] = bx | (by << 8) | (bz << 16) | (1 << 24);
      }
      if (t == 0) nit[0] = 12 * pre[4];
    }
    return;
  }
  // gather: masked K/V rows -> compacted f16
  const int r = x - 4610, b = r >> 11, s = r & (SS - 1);
  if (!mask[b * SS + s]) return;
  const int p = pos[b * SS + s];
  float4 kv = ((const float4*)(K + ((long)b * SS + s) * EE))[t];
  float4 vv = ((const float4*)(V + ((long)b * SS + s) * EE))[t];
  f16x4 ko, vo;
  ko[0] = (f16)kv.x; ko[1] = (f16)kv.y; ko[2] = (f16)kv.z; ko[3] = (f16)kv.w;
  vo[0] = (f16)vv.x; vo[1] = (f16)vv.y; vo[2] = (f16)vv.z; vo[3] = (f16)vv.w;
  ((f16x4*)(Kc + ((long)b * SS + p) * EE))[t] = ko;
  ((f16x4*)(Vc + ((long)b * SS + p) * EE))[t] = vo;
}

// ---------- shared 256x128 8-phase GEMM core ----------
// Swizzle: 16B-slot ^= (row&7) on global SOURCE and ds_read addr.
__device__ __forceinline__ void stage64(const f16* g, long K, f16* l, int h, int t) {
  int rr = t >> 3, sp = t & 7;
  int row = h * 64 + rr;
  int sl = sp ^ (rr & 7);
  gl_lds16(g + (long)row * K + (sl << 3), (char*)l + ((row << 6) + (sp << 3)) * 2);
}

__device__ __forceinline__ void read_a(f16x8 (&d)[4][2], const f16* base, int q,
                                       int wm, int l15, int l4) {
#pragma unroll
  for (int mf = 0; mf < 4; ++mf)
#pragma unroll
    for (int kk = 0; kk < 2; ++kk) {
      int row = wm * 128 + (q * 4 + mf) * 16 + l15;
      int sl = kk * 4 + l4;
      d[mf][kk] = *(const f16x8*)(base + row * 64 + ((sl ^ (row & 7)) << 3));
    }
}

__device__ __forceinline__ void read_b1(f16x8 (&d)[2], const f16* base, int f,
                                        int wn, int l15, int l4) {
#pragma unroll
  for (int kk = 0; kk < 2; ++kk) {
    int row = wn * 32 + f * 16 + l15;
    int sl = kk * 4 + l4;
    d[kk] = *(const f16x8*)(base + row * 64 + ((sl ^ (row & 7)) << 3));
  }
}

__device__ __forceinline__ void mfma_n(f32x4 (&acc)[8][2], const f16x8 (&Af)[4][2],
                                       const f16x8 (&Bf)[2], int q, int f) {
#pragma unroll
  for (int mf = 0; mf < 4; ++mf)
#pragma unroll
    for (int kk = 0; kk < 2; ++kk)
      acc[q * 4 + mf][f] = __builtin_amdgcn_mfma_f32_16x16x32_f16(
          Af[mf][kk], Bf[kk], acc[q * 4 + mf][f], 0, 0, 0);
}

// 8 waves 2M x 4N; 6 loads/K-tile; counted vmcnt(6) gates (R4-verified).
__device__ __forceinline__ void n128_core(f32x4 (&acc)[8][2], const f16* Ag,
                                          const f16* Bg, long L, int NT,
                                          f16* lds, int tid, int wm, int wn,
                                          int l15, int l4) {
  f16* As0 = lds;
  f16* As1 = lds + 16384;
  f16* Bs0 = lds + 32768;
  f16* Bs1 = lds + 40960;
  f16x8 a[4][2], b[2], b2[2];
  const int NIT = NT >> 1;

  stage64(Bg, L, Bs0, 0, tid); stage64(Bg, L, Bs0, 1, tid);
#pragma unroll
  for (int h = 0; h < 4; ++h) stage64(Ag, L, As0, h, tid);
  stage64(Bg + 64, L, Bs1, 0, tid); stage64(Bg + 64, L, Bs1, 1, tid);
#pragma unroll
  for (int h = 0; h < 4; ++h) stage64(Ag + 64, L, As1, h, tid);
  WAITV6();
  BAR();

  for (int i = 0; i < NIT; ++i) {
    int t2 = 2 * i + 2, t3 = 2 * i + 3;
    long k2 = (long)((t2 < NT) ? t2 : NT - 1) << 6;
    long k3 = (long)((t3 < NT) ? t3 : NT - 1) << 6;
    read_a(a, As0, 0, wm, l15, l4);
    read_b1(b, Bs0, 0, wn, l15, l4);
    BAR(); PRIO1(); mfma_n(acc, a, b, 0, 0); PRIO0(); BAR();
    read_b1(b2, Bs0, 1, wn, l15, l4);
    BAR(); PRIO1(); mfma_n(acc, a, b2, 0, 1); PRIO0(); BAR();
    read_a(a, As0, 1, wm, l15, l4);
    stage64(Bg + k2, L, Bs0, 0, tid); stage64(Bg + k2, L, Bs0, 1, tid);
    BAR(); PRIO1(); mfma_n(acc, a, b2, 1, 1); PRIO0(); BAR();
#pragma unroll
    for (int h = 0; h < 4; ++h) stage64(Ag + k2, L, As0, h, tid);
    BAR(); PRIO1(); mfma_n(acc, a, b, 1, 0); PRIO0();
    WAITV6();
    BAR();
    read_a(a, As1, 0, wm, l15, l4);
    read_b1(b, Bs1, 0, wn, l15, l4);
    BAR(); PRIO1(); mfma_n(acc, a, b, 0, 0); PRIO0(); BAR();
    read_b1(b2, Bs1, 1, wn, l15, l4);
    BAR(); PRIO1(); mfma_n(acc, a, b2, 0, 1); PRIO0(); BAR();
    read_a(a, As1, 1, wm, l15, l4);
    stage64(Bg + k3, L, Bs1, 0, tid); stage64(Bg + k3, L, Bs1, 1, tid);
    BAR(); PRIO1(); mfma_n(acc, a, b2, 1, 1); PRIO0(); BAR();
#pragma unroll
    for (int h = 0; h < 4; ++h) stage64(Ag + k3, L, As1, h, tid);
    BAR(); PRIO1(); mfma_n(acc, a, b, 1, 0); PRIO0();
    WAITV6();
    BAR();
  }
  WAITV0();
}

// ---------- uber: persistent QK+WV over device-built item list ----------
// kind 0: P' = (col<count)?exp(acc/32):0, rowsum atomic. kind 1: VWt f16 store.
__global__ __launch_bounds__(512, 1) void uber(const f16* __restrict__ Qh,
                                               const f16* __restrict__ Kc,
                                               const f16* __restrict__ Vc,
                                               const f16* __restrict__ Wh,
                                               f16* __restrict__ P,
                                               f16* __restrict__ VWt,
                                               float* __restrict__ rowsum,
                                               const int2* __restrict__ cnt,
                                               const int* __restrict__ items,
                                               const int* __restrict__ nit) {
  extern __shared__ f16 lds[];
  const int tid = threadIdx.x;
  const int lane = tid & 63, wv = tid >> 6;
  const int wm = wv >> 2, wn = wv & 3;
  const int l15 = lane & 15, l4 = lane >> 4;
  const int n = nit[0];

  for (int idx = blockIdx.x; idx < n; idx += 256) {
    const int it = items[idx];
    const int bx = it & 255, by = (it >> 8) & 255, bz = (it >> 16) & 255;
    const int kind = it >> 24;
    const long m0 = (long)by * 256;
    const long n0 = (long)bx * 128;
    const f16* Ag = kind ? (Wh + m0 * EE) : (Qh + (long)bz * SS * EE + m0 * EE);
    const f16* Bg = (kind ? Vc : Kc) + (long)bz * SS * EE + n0 * EE;

    f32x4 acc[8][2] = {};
    n128_core(acc, Ag, Bg, EE, EE >> 6, lds, tid, wm, wn, l15, l4);

    const long crow = m0 + wm * 128 + l4 * 4;
    const long ccol = n0 + wn * 32 + l15;
    if (kind == 0) {
      const int count = cnt[bz].x;
      f16* Co = P + (long)bz * SS * SS;
      float* rs = rowsum + (bz << 11);
      const float scale = 1.0f / 32.0f;
      int mv[2];
#pragma unroll
      for (int nf = 0; nf < 2; ++nf) mv[nf] = (ccol + nf * 16) < count;
#pragma unroll
      for (int mf = 0; mf < 8; ++mf)
#pragma unroll
        for (int jj = 0; jj < 4; ++jj) {
          float rp = 0.f;
#pragma unroll
          for (int nf = 0; nf < 2; ++nf) {
            float p = mv[nf] ? __expf(acc[mf][nf][jj] * scale) : 0.f;
            Co[(crow + mf * 16 + jj) * SS + ccol + nf * 16] = (f16)p;
            rp += p;
          }
          rp += __shfl_xor(rp, 1); rp += __shfl_xor(rp, 2);
          rp += __shfl_xor(rp, 4); rp += __shfl_xor(rp, 8);
          if (l15 == 0) atomicAdd(&rs[crow + mf * 16 + jj], rp);
        }
    } else {
      f16* Co = VWt + (long)bz * EE * SS;
#pragma unroll
      for (int mf = 0; mf < 8; ++mf)
#pragma unroll
        for (int nf = 0; nf < 2; ++nf)
#pragma unroll
          for (int jj = 0; jj < 4; ++jj)
            Co[(crow + mf * 16 + jj) * SS + ccol + nf * 16] = (f16)acc[mf][nf][jj];
    }
  }
}

// ---------- PV: out = (P' @ VWt^T) / rowsum + bias (f32) ----------
__global__ __launch_bounds__(512, 1) void pv128(const f16* __restrict__ P,
                                                const f16* __restrict__ VWt,
                                                float* __restrict__ out,
                                                const float* __restrict__ bias,
                                                const float* __restrict__ rowsum,
                                                const int2* __restrict__ cnt) {
  extern __shared__ f16 lds[];
  // XCD swizzle decode, grid (8,8,4): y-row per XCD
  int d = blockIdx.x + blockIdx.y * 8 + blockIdx.z * 64;
  int c = d & 7, j = d >> 3;
  const int bx = j & 7, by = c, bz = j >> 3;
  int2 cc = cnt[bz];
  const int padded = cc.y;
  if (padded <= 0) return;  // never taken; forces cnt-load wait before staging
  const long m0 = (long)by * 256;
  const long n0 = (long)bx * 128;
  const int tid = threadIdx.x;
  const int lane = tid & 63, wv = tid >> 6;
  const int wm = wv >> 2, wn = wv & 3;
  const int l15 = lane & 15, l4 = lane >> 4;
  const f16* Ag = P + (long)bz * SS * SS + m0 * SS;
  const f16* Bg = VWt + (long)bz * EE * SS + n0 * SS;

  f32x4 acc[8][2] = {};
  n128_core(acc, Ag, Bg, SS, padded >> 6, lds, tid, wm, wn, l15, l4);

  const long crow = m0 + wm * 128 + l4 * 4;
  const long ccol = n0 + wn * 32 + l15;
  float* Co = out + (long)bz * SS * EE;
  const float* rs = rowsum + (bz << 11);
  float bv[2];
#pragma unroll
  for (int nf = 0; nf < 2; ++nf) bv[nf] = bias[ccol + nf * 16];
#pragma unroll
  for (int mf = 0; mf < 8; ++mf)
#pragma unroll
    for (int jj = 0; jj < 4; ++jj) {
      float inv = 1.f / rs[crow + mf * 16 + jj];
#pragma unroll
      for (int nf = 0; nf < 2; ++nf)
        Co[(crow + mf * 16 + jj) * EE + ccol + nf * 16] =
            acc[mf][nf][jj] * inv + bv[nf];
    }
}

extern "C" void kernel_launch(void* const* d_in, const int* in_sizes, int n_in,
                              void* d_out, int out_size, void* d_ws, size_t ws_size,
                              hipStream_t stream) {
  const float* V = (const float*)d_in[0];
  const float* Kin = (const float*)d_in[1];
  const float* Q = (const float*)d_in[2];
  const int* mask = (const int*)d_in[3];
  const float* W = (const float*)d_in[4];
  const float* bias = (const float*)d_in[5];
  float* out = (float*)d_out;

  const long NE = (long)BB * SS * EE;  // 8388608
  f16* Qh = (f16*)d_ws;                  // NE
  f16* Kc = Qh + NE;                     // NE (compacted K, f16)
  f16* Vc = Kc + NE;                     // NE (compacted V, f16)
  f16* Wh = Vc + NE;                     // EE*EE
  f16* VWt = Wh + (long)EE * EE;         // NE ([B][E][S] stride SS, cols<padded valid)
  f16* P = VWt + NE;                     // 2*NE ([B][S][S] stride SS, cols<padded valid)
  float* rowsum = (float*)(P + (long)BB * SS * SS);  // B*S
  int* pos = (int*)(rowsum + (long)BB * SS);         // B*S
  int2* cnt = (int2*)(pos + (long)BB * SS);          // B
  int* items = (int*)(cnt + BB);                     // <=1024
  int* nit = items + 1024;                           // 1

  const size_t LDS_N = 98304;
  hipFuncSetAttribute((const void*)uber, hipFuncAttributeMaxDynamicSharedMemorySize, LDS_N);
  hipFuncSetAttribute((const void*)pv128, hipFuncAttributeMaxDynamicSharedMemorySize, LDS_N);

  prep<<<BB, 256, 0, stream>>>(mask, pos, cnt, Kc, Vc);
  prep2<<<4610 + BB * SS, 256, 0, stream>>>(Q, W, Kin, V, mask, pos, cnt,
                                            Qh, Wh, Kc, Vc, rowsum, items, nit);

  // QK (P'=exp, rowsum) + WV (VWt=W@Vc^T) as one balanced persistent launch
  uber<<<256, 512, LDS_N, stream>>>(Qh, Kc, Vc, Wh, P, VWt, rowsum, cnt, items, nit);

  // out = (P' @ VWt^T) / rowsum + bias
  pv128<<<dim3(8, 8, BB), 512, LDS_N, stream>>>(P, VWt, out, bias, rowsum, cnt);
}